// Round 2
// baseline (671.651 us; speedup 1.0000x reference)
//
#include <hip/hip_runtime.h>
#include <hip/hip_bf16.h>

// ---------------------------------------------------------------------------
// KV-cached MHA, MI355X. Round 2:
//  * prep: single fused pass (cache copy + all bf16 cvt); cache bf16 mirrors
//    now HEAD-MAJOR [b][h][t][128] for sequential attn staging.
//  * gemm_qkv: Q/K/V projections fused into ONE dispatch over A-concat
//    [12288][2048] (grid 1536 = 6 blocks/CU vs 3x512=2/CU).
//  * attn_k: KVBLK=64 (half the barriers; dropped needless P barrier —
//    Pw is per-wave), K staged via global_load_lds with pre-swizzled global
//    source (m173), V/P LDS layouts conflict-free at 16-lane-phase
//    granularity, XCD-grouped dispatch map (same (b,h) -> same XCD, per-CU
//    trip sums exactly constant = 34).
// ---------------------------------------------------------------------------

typedef __bf16 bf16x8 __attribute__((ext_vector_type(8)));
typedef __bf16 bf16x4 __attribute__((ext_vector_type(4)));
typedef unsigned short u16x8 __attribute__((ext_vector_type(8)));
typedef float  f32x4  __attribute__((ext_vector_type(4)));
typedef unsigned int u32;

#define MFMA16(a, b, c) __builtin_amdgcn_mfma_f32_16x16x32_bf16((a), (b), (c), 0, 0, 0)

__device__ __forceinline__ void async16(__bf16* lds, const __bf16* g) {
    __builtin_amdgcn_global_load_lds(
        (__attribute__((address_space(1))) void*)g,
        (__attribute__((address_space(3))) void*)lds, 16, 0, 0);
}

// ---------------------------------------------------------------------------
// prep: one grid-stride BW pass.
//  seg A (4194304 units): cache fp32 copy -> new_k/new_v + bf16 head-major
//                         mirrors ck_bf/cv_bf
//  seg B (3145728 units): q/k/v fp32 -> bf16 (8 elems/unit)
//  seg C (2097152 units): Wq/Wk/Wv/Wo fp32 -> bf16 (8 elems/unit)
// ---------------------------------------------------------------------------
__global__ __launch_bounds__(256) void prep(
    const float* __restrict__ q, const float* __restrict__ k, const float* __restrict__ v,
    const float* __restrict__ wq, const float* __restrict__ wk,
    const float* __restrict__ wv, const float* __restrict__ wo,
    const float* __restrict__ ck, const float* __restrict__ cv,
    float* __restrict__ nk, float* __restrict__ nv,
    __bf16* __restrict__ dq, __bf16* __restrict__ dk, __bf16* __restrict__ dv,
    __bf16* __restrict__ dwq, __bf16* __restrict__ dwk,
    __bf16* __restrict__ dwv, __bf16* __restrict__ dwo,
    __bf16* __restrict__ ckb, __bf16* __restrict__ cvb) {
    const int nthreads = gridDim.x * blockDim.x;
    for (int i = blockIdx.x * blockDim.x + threadIdx.x; i < 9437184; i += nthreads) {
        if (i < 4194304) {
            const int sel = i >> 21;
            const int j = i & 2097151;
            const int dh4 = j & 31;
            const int t = (j >> 5) & 1023;
            const int h = (j >> 15) & 15;
            const int b = j >> 19;
            const float* src = sel ? cv : ck;
            float* dst = sel ? nv : nk;
            __bf16* dstb = sel ? cvb : ckb;
            const size_t si = ((size_t)(b << 10) + t) * 2048 + (h << 7) + (dh4 << 2);
            const size_t di = ((size_t)b << 22) + ((size_t)h << 18) + (t << 7) + (dh4 << 2);
            const size_t bi = (((size_t)(b * 16 + h) * 1024 + t) << 7) + (dh4 << 2);
            const f32x4 x = *(const f32x4*)&src[si];
            *(f32x4*)&dst[di] = x;
            bf16x4 bx;
#pragma unroll
            for (int e = 0; e < 4; e++) bx[e] = (__bf16)x[e];
            *(bf16x4*)&dstb[bi] = bx;
        } else {
            const float* s;
            __bf16* d;
            int off;
            if (i < 7340032) {
                const int ii = i - 4194304;
                const int r = ii >> 20;
                off = ii & 1048575;
                s = (r == 0) ? q : (r == 1) ? k : v;
                d = (r == 0) ? dq : (r == 1) ? dk : dv;
            } else {
                const int ii = i - 7340032;
                const int r = ii >> 19;
                off = ii & 524287;
                s = (r == 0) ? wq : (r == 1) ? wk : (r == 2) ? wv : wo;
                d = (r == 0) ? dwq : (r == 1) ? dwk : (r == 2) ? dwv : dwo;
            }
            const f32x4 x0 = *(const f32x4*)(s + (size_t)off * 8);
            const f32x4 x1 = *(const f32x4*)(s + (size_t)off * 8 + 4);
            bf16x8 o;
#pragma unroll
            for (int j2 = 0; j2 < 4; j2++) {
                o[j2]     = (__bf16)x0[j2];
                o[j2 + 4] = (__bf16)x1[j2];
            }
            *(bf16x8*)(d + (size_t)off * 8) = o;
        }
    }
}

// ---------------------------------------------------------------------------
// Fused QKV GEMM: C[12288,2048] = A_cat @ Wseg^T + bias_seg, m97 structure.
// seg = m_blk/32: 0 -> ws_q bf16 [b][h][1024][128]; 1/2 -> new_k/new_v fp32
// [b][h][2048][128] at t offset +1024.
// ---------------------------------------------------------------------------
__global__ __launch_bounds__(256) void gemm_qkv(
    const __bf16* __restrict__ A,
    const __bf16* __restrict__ Wqb, const __bf16* __restrict__ Wkb,
    const __bf16* __restrict__ Wvb,
    const float* __restrict__ bq, const float* __restrict__ bk,
    const float* __restrict__ bv,
    __bf16* __restrict__ ws_q, float* __restrict__ new_k,
    float* __restrict__ new_v) {
    constexpr int K = 2048;
    __shared__ __bf16 aT[128 * 32];
    __shared__ __bf16 bT[128 * 32];

    const int tid = threadIdx.x;
    const int w = tid >> 6;
    const int lane = tid & 63;

    // 1536 blocks, chunked XCD swizzle (1536/8 = 192, bijective)
    const int lin = (blockIdx.y << 4) | blockIdx.x;
    const int swz = (lin & 7) * 192 + (lin >> 3);
    const int mb = swz >> 4, nb = swz & 15;
    const int m0 = mb << 7, n0 = nb << 7;
    const int seg = mb >> 5;   // 0=Q 1=K 2=V
    const __bf16* W = (seg == 0) ? Wqb : (seg == 1) ? Wkb : Wvb;
    const float* bias = (seg == 0) ? bq : (seg == 1) ? bk : bv;

    const int wr = w >> 1, wc = w & 1;
    const int g = lane >> 4, c = lane & 15;

    const int srow = w * 32 + (lane >> 2);
    const int kch = (lane & 3) * 8;
    const __bf16* gA0 = A + (size_t)(m0 + srow) * K + kch;
    const __bf16* gB0 = W + (size_t)(n0 + srow) * K + kch;
    __bf16* lA0 = &aT[w * 1024];
    __bf16* lB0 = &bT[w * 1024];

    f32x4 acc[4][4] = {};
    const int arow = wr * 64 + c;
    const int brow = wc * 64 + c;
    const int koff = g * 8;

    for (int k0 = 0; k0 < K; k0 += 32) {
        async16(lA0,       gA0 + k0);
        async16(lA0 + 512, gA0 + 16 * K + k0);
        async16(lB0,       gB0 + k0);
        async16(lB0 + 512, gB0 + 16 * K + k0);
        __syncthreads();
        bf16x8 af[4], bfr[4];
#pragma unroll
        for (int t = 0; t < 4; t++) {
            af[t]  = *(const bf16x8*)&aT[(arow + t * 16) * 32 + koff];
            bfr[t] = *(const bf16x8*)&bT[(brow + t * 16) * 32 + koff];
        }
#pragma unroll
        for (int ti = 0; ti < 4; ti++)
#pragma unroll
            for (int tj = 0; tj < 4; tj++)
                acc[ti][tj] = MFMA16(af[ti], bfr[tj], acc[ti][tj]);
        __syncthreads();
    }

#pragma unroll
    for (int tj = 0; tj < 4; tj++) {
        const int gcol = n0 + wc * 64 + tj * 16 + c;
        const float bv2 = bias[gcol];
        const int h = gcol >> 7, dh = gcol & 127;
#pragma unroll
        for (int ti = 0; ti < 4; ti++) {
            const int growb = m0 + wr * 64 + ti * 16 + g * 4;
#pragma unroll
            for (int r = 0; r < 4; r++) {
                const float vv = acc[ti][tj][r] + bv2;
                const int lrow = (growb + r) - (seg << 12);  // 0..4095 in-seg
                const int b = lrow >> 10, t = lrow & 1023;
                if (seg == 0)
                    ws_q[(((size_t)(b * 16 + h) * 1024) + t) * 128 + dh] = (__bf16)vv;
                else if (seg == 1)
                    new_k[(((size_t)(b * 16 + h) * 2048) + 1024 + t) * 128 + dh] = vv;
                else
                    new_v[(((size_t)(b * 16 + h) * 2048) + 1024 + t) * 128 + dh] = vv;
            }
        }
    }
}

// ---------------------------------------------------------------------------
// Output projection GEMM (m97 structure, 512 blocks, XCD swizzle)
// ---------------------------------------------------------------------------
__global__ __launch_bounds__(256) void gemm_o(const __bf16* __restrict__ A,
                                              const __bf16* __restrict__ W,
                                              const float* __restrict__ bias,
                                              float* __restrict__ C) {
    constexpr int K = 2048;
    __shared__ __bf16 aT[128 * 32];
    __shared__ __bf16 bT[128 * 32];

    const int tid = threadIdx.x;
    const int w = tid >> 6;
    const int lane = tid & 63;

    const int lin = (blockIdx.y << 4) | blockIdx.x;
    const int swz = ((lin & 7) << 6) | (lin >> 3);
    const int m0 = (swz >> 4) << 7;
    const int n0 = (swz & 15) << 7;

    const int wr = w >> 1, wc = w & 1;
    const int g = lane >> 4, c = lane & 15;

    const int srow = w * 32 + (lane >> 2);
    const int kch = (lane & 3) * 8;
    const __bf16* gA0 = A + (size_t)(m0 + srow) * K + kch;
    const __bf16* gB0 = W + (size_t)(n0 + srow) * K + kch;
    __bf16* lA0 = &aT[w * 1024];
    __bf16* lB0 = &bT[w * 1024];

    f32x4 acc[4][4] = {};
    const int arow = wr * 64 + c;
    const int brow = wc * 64 + c;
    const int koff = g * 8;

    for (int k0 = 0; k0 < K; k0 += 32) {
        async16(lA0,       gA0 + k0);
        async16(lA0 + 512, gA0 + 16 * K + k0);
        async16(lB0,       gB0 + k0);
        async16(lB0 + 512, gB0 + 16 * K + k0);
        __syncthreads();
        bf16x8 af[4], bfr[4];
#pragma unroll
        for (int t = 0; t < 4; t++) {
            af[t]  = *(const bf16x8*)&aT[(arow + t * 16) * 32 + koff];
            bfr[t] = *(const bf16x8*)&bT[(brow + t * 16) * 32 + koff];
        }
#pragma unroll
        for (int ti = 0; ti < 4; ti++)
#pragma unroll
            for (int tj = 0; tj < 4; tj++)
                acc[ti][tj] = MFMA16(af[ti], bfr[tj], acc[ti][tj]);
        __syncthreads();
    }

#pragma unroll
    for (int tj = 0; tj < 4; tj++) {
        const int gcol = n0 + wc * 64 + tj * 16 + c;
        const float bv = bias[gcol];
#pragma unroll
        for (int ti = 0; ti < 4; ti++) {
            const int growb = m0 + wr * 64 + ti * 16 + g * 4;
#pragma unroll
            for (int r = 0; r < 4; r++)
                C[(size_t)(growb + r) * 2048 + gcol] = acc[ti][tj][r] + bv;
        }
    }
}

// ---------------------------------------------------------------------------
// Flash attention, KVBLK=64, causal (key <= qrow). 4 waves x 16 q-rows.
// LDS: Kt [64][128] bf16 chunk-swizzled (ch ^= key&7), staged via
//      global_load_lds with pre-swizzled global source (linear dest);
//      Vt32 [128 dh][32 kp] u32 key-pairs, col = ((kp>>2)^(d&7))<<2|(kp&3);
//      Pw per-wave [16][64] chunk-swizzled (cc ^= row&7).
// All LDS ops conflict-free per 16-lane phase. 2 barriers per 64-key trip.
// Dispatch map: bh = lin bits0-5 (same bh -> same XCD, L2-resident panels);
// qb from bits6-9 with middle-quartile reflection -> per-CU trip sum = 34.
// ---------------------------------------------------------------------------
__global__ __launch_bounds__(256) void attn_k(const __bf16* __restrict__ Qw,
                                              const __bf16* __restrict__ cK,
                                              const __bf16* __restrict__ cV,
                                              __bf16* __restrict__ O) {
    __shared__ __bf16 Kt[64 * 128];     // 16 KB
    __shared__ u32    Vt32[128 * 32];   // 16 KB
    __shared__ __bf16 Pw[4][16 * 64];   // 8 KB

    const int tid = threadIdx.x;
    const int w = tid >> 6;
    const int lane = tid & 63;
    const int g = lane >> 4, c = lane & 15;

    const int lin = blockIdx.x + (blockIdx.y << 4) + (blockIdx.z << 8);
    const int bh = (lin & 7) | (((lin >> 3) & 7) << 3);
    const int qraw = (lin >> 6) & 15;
    const int tt = qraw >> 2;
    const int qb = (tt == 1 || tt == 2) ? 15 - qraw : qraw;
    const int b = bh >> 4, h = bh & 15;
    const int q0 = qb << 6;
    const float inv_scale = 0.08838834764831845f; // 1/sqrt(128)

    const __bf16* qbase = Qw + (((size_t)(b * 16 + h) * 1024) + q0 + w * 16) * 128;
    bf16x8 qf[4];
#pragma unroll
    for (int dc = 0; dc < 4; dc++)
        qf[dc] = *(const bf16x8*)&qbase[c * 128 + dc * 32 + g * 8];

    f32x4 accO[8] = {};
    float m_run[4], l_run[4];
#pragma unroll
    for (int r = 0; r < 4; r++) { m_run[r] = -1e30f; l_run[r] = 0.0f; }

    const int trips = qb + 1;
    const __bf16* kb = cK + (size_t)(b * 16 + h) * 1024 * 128;
    const __bf16* vb = cV + (size_t)(b * 16 + h) * 1024 * 128;

    // K staging via gload_lds: wave w fills Kt rows [w*16, w*16+16), 4 calls.
    // LDS linear (key,ch') holds global chunk ch = ch' ^ (key&7)  -> source
    // offset per lane = key*128 + ((chl ^ (key&7))<<3), key = w*16+j*4+(l>>4).
    const int chl = lane & 15;
    size_t ksrc[4];
    __bf16* kdst[4];
#pragma unroll
    for (int j = 0; j < 4; j++) {
        const int key = w * 16 + j * 4 + (lane >> 4);
        ksrc[j] = (size_t)key * 128 + ((chl ^ (key & 7)) << 3);
        kdst[j] = &Kt[(w * 16 + j * 4) * 128];
    }

    // V staging: thread owns key pair kp, dh block db*16..+15
    const int kp = ((tid & 7) << 2) | ((tid >> 3) & 3);
    const int db = tid >> 5;
    const __bf16* vbase = vb + (size_t)(2 * kp) * 128 + db * 16;

    for (int kt = 0; kt < trips; kt++) {
        const int k0 = kt * 64;
        // V register loads issued before barrier (overlap prior compute tail)
        const __bf16* vr = vbase + (size_t)k0 * 128;
        const bf16x8 v0a = *(const bf16x8*)&vr[0];
        const bf16x8 v0b = *(const bf16x8*)&vr[8];
        const bf16x8 v1a = *(const bf16x8*)&vr[128];
        const bf16x8 v1b = *(const bf16x8*)&vr[136];
        __syncthreads();   // #1: prior trip's Kt/Vt reads complete
#pragma unroll
        for (int j = 0; j < 4; j++)
            async16(kdst[j], kb + (size_t)k0 * 128 + ksrc[j]);
        {
            const u16x8 a0 = __builtin_bit_cast(u16x8, v0a);
            const u16x8 a1 = __builtin_bit_cast(u16x8, v0b);
            const u16x8 b0 = __builtin_bit_cast(u16x8, v1a);
            const u16x8 b1 = __builtin_bit_cast(u16x8, v1b);
            const int colhi = kp & 3;
            const int kph = kp >> 2;
#pragma unroll
            for (int j = 0; j < 8; j++)
                Vt32[(db * 16 + j) * 32 + ((kph ^ j) << 2) + colhi] =
                    (u32)a0[j] | ((u32)b0[j] << 16);
#pragma unroll
            for (int j = 0; j < 8; j++)
                Vt32[(db * 16 + 8 + j) * 32 + ((kph ^ j) << 2) + colhi] =
                    (u32)a1[j] | ((u32)b1[j] << 16);
        }
        __syncthreads();   // #2: drains gload_lds vmcnt + V ds_writes

        // S = Q @ K^T : 4 x 16-key tiles
        f32x4 s_acc[4] = {};
#pragma unroll
        for (int nt = 0; nt < 4; nt++) {
            const int krow = nt * 16 + c;
            const int ks = krow & 7;
#pragma unroll
            for (int dc = 0; dc < 4; dc++) {
                const bf16x8 kf =
                    *(const bf16x8*)&Kt[krow * 128 + (((dc * 4 + g) ^ ks) << 3)];
                s_acc[nt] = MFMA16(qf[dc], kf, s_acc[nt]);
            }
        }

        // mask + online softmax (lane holds rows g*4+r, cols nt*16+c)
        float p[4][4], alpha[4];
#pragma unroll
        for (int r = 0; r < 4; r++) {
            const int qrow = q0 + w * 16 + g * 4 + r;
            float s[4];
#pragma unroll
            for (int nt = 0; nt < 4; nt++)
                s[nt] = (k0 + nt * 16 + c <= qrow) ? s_acc[nt][r] * inv_scale : -1e30f;
            float rm = fmaxf(fmaxf(s[0], s[1]), fmaxf(s[2], s[3]));
            rm = fmaxf(rm, __shfl_xor(rm, 1));
            rm = fmaxf(rm, __shfl_xor(rm, 2));
            rm = fmaxf(rm, __shfl_xor(rm, 4));
            rm = fmaxf(rm, __shfl_xor(rm, 8));
            const float mnew = fmaxf(m_run[r], rm);
            alpha[r] = __expf(m_run[r] - mnew);
            float ps = 0.0f;
#pragma unroll
            for (int nt = 0; nt < 4; nt++) {
                p[nt][r] = __expf(s[nt] - mnew);
                ps += p[nt][r];
            }
            ps += __shfl_xor(ps, 1);
            ps += __shfl_xor(ps, 2);
            ps += __shfl_xor(ps, 4);
            ps += __shfl_xor(ps, 8);
            l_run[r] = alpha[r] * l_run[r] + ps;
            m_run[r] = mnew;
        }
#pragma unroll
        for (int nt2 = 0; nt2 < 8; nt2++)
#pragma unroll
            for (int r = 0; r < 4; r++)
                accO[nt2][r] *= alpha[r];

        // P -> per-wave LDS (chunk-swizzled), no block barrier needed
#pragma unroll
        for (int nt = 0; nt < 4; nt++)
#pragma unroll
            for (int r = 0; r < 4; r++) {
                const int row = g * 4 + r;
                const int cc = (nt * 2 + (c >> 3)) ^ (row & 7);
                Pw[w][row * 64 + (cc << 3) + (c & 7)] = (__bf16)p[nt][r];
            }
        asm volatile("s_waitcnt lgkmcnt(0)" ::: "memory");
        __builtin_amdgcn_sched_barrier(0);

        bf16x8 pf[2];
#pragma unroll
        for (int s2 = 0; s2 < 2; s2++)
            pf[s2] = *(const bf16x8*)&Pw[w][c * 64 + (((s2 * 4 + g) ^ (c & 7)) << 3)];
#pragma unroll
        for (int nt2 = 0; nt2 < 8; nt2++) {
            const int d = nt2 * 16 + c;
#pragma unroll
            for (int s2 = 0; s2 < 2; s2++) {
                const bf16x8 vf = *(const bf16x8*)&Vt32[d * 32 +
                    (((s2 * 4 + g) ^ (d & 7)) << 2)];
                accO[nt2] = MFMA16(pf[s2], vf, accO[nt2]);
            }
        }
    }

    // epilogue: normalize, store bf16 to ws_attn [4096][2048]
#pragma unroll
    for (int nt2 = 0; nt2 < 8; nt2++)
#pragma unroll
        for (int r = 0; r < 4; r++) {
            const float v = accO[nt2][r] / l_run[r];
            const int row = b * 1024 + q0 + w * 16 + g * 4 + r;
            const int col = h * 128 + nt2 * 16 + c;
            O[(size_t)row * 2048 + col] = (__bf16)v;
        }
}

// ---------------------------------------------------------------------------
extern "C" void kernel_launch(void* const* d_in, const int* in_sizes, int n_in,
                              void* d_out, int out_size, void* d_ws, size_t ws_size,
                              hipStream_t stream) {
    const float* query       = (const float*)d_in[0];
    const float* key         = (const float*)d_in[1];
    const float* value       = (const float*)d_in[2];
    const float* cache_key   = (const float*)d_in[3];
    const float* cache_value = (const float*)d_in[4];
    const float* Wq = (const float*)d_in[5];
    const float* bq = (const float*)d_in[6];
    const float* Wk = (const float*)d_in[7];
    const float* bk = (const float*)d_in[8];
    const float* Wv = (const float*)d_in[9];
    const float* bv = (const float*)d_in[10];
    const float* Wo = (const float*)d_in[11];
    const float* bo = (const float*)d_in[12];

    float* out   = (float*)d_out;              // [4096][2048] fp32
    float* new_k = out + 8388608;              // [B][H][2048][128] fp32
    float* new_v = out + 25165824;

    // workspace (bf16 elems): q_bf/k_bf/v_bf MUST be contiguous (A-concat)
    __bf16* p = (__bf16*)d_ws;
    __bf16* ws_q    = p; p += 8388608;         // [b][h][1024][128]
    __bf16* ws_attn = p; p += 8388608;         // [4096][2048]
    __bf16* q_bf    = p; p += 8388608;         // A-concat rows 0..4095
    __bf16* k_bf    = p; p += 8388608;         //               4096..8191
    __bf16* v_bf    = p; p += 8388608;         //               8192..12287
    __bf16* wq_bf   = p; p += 4194304;
    __bf16* wk_bf   = p; p += 4194304;
    __bf16* wv_bf   = p; p += 4194304;
    __bf16* wo_bf   = p; p += 4194304;
    __bf16* ck_bf   = p; p += 8388608;         // [b][h][1024][128] head-major
    __bf16* cv_bf   = p;

    prep<<<4096, 256, 0, stream>>>(query, key, value, Wq, Wk, Wv, Wo,
                                   cache_key, cache_value, new_k, new_v,
                                   q_bf, k_bf, v_bf, wq_bf, wk_bf, wv_bf, wo_bf,
                                   ck_bf, cv_bf);
    gemm_qkv<<<dim3(16, 96), 256, 0, stream>>>(q_bf, wq_bf, wk_bf, wv_bf,
                                               bq, bk, bv, ws_q, new_k, new_v);
    attn_k<<<dim3(16, 16, 4), 256, 0, stream>>>(ws_q, ck_bf, cv_bf, ws_attn);
    gemm_o<<<dim3(16, 32), 256, 0, stream>>>(ws_attn, wo_bf, bo, out);
}

// Round 3
// 640.424 us; speedup vs baseline: 1.0488x; 1.0488x over previous
//
#include <hip/hip_runtime.h>
#include <hip/hip_bf16.h>

// ---------------------------------------------------------------------------
// KV-cached MHA, MI355X. Round 3:
//  * gemm8: 256x256 8-phase schedule (T3+T4+T2+T5): BK=64, 8 waves, 128 KB
//    dbuf LDS (dynamic + hipFuncSetAttribute), subtiled 16x32 LDS layout with
//    XOR swizzle via pre-swizzled global_load_lds source, raw s_barrier +
//    counted vmcnt(4) (vmcnt(0) only in 2-tile tail), setprio around MFMA.
//    Used for fused QKV (384 blocks) and out-proj (128 blocks).
//    XCD map: nb = blockIdx%8 -> each XCD owns one W n-panel (W read once).
//  * attn_k: revert to round-1 structure (measured 112us) but staged from
//    bf16 HEAD-MAJOR cache mirrors (contiguous 2KB/wave reads, half fetch).
//  * prep unchanged (fused copy+cvt, head-major bf16 cache mirrors).
// ---------------------------------------------------------------------------

typedef __bf16 bf16x8 __attribute__((ext_vector_type(8)));
typedef __bf16 bf16x4 __attribute__((ext_vector_type(4)));
typedef unsigned short u16x8 __attribute__((ext_vector_type(8)));
typedef float  f32x4  __attribute__((ext_vector_type(4)));
typedef unsigned int u32;

#define MFMA16(a, b, c) __builtin_amdgcn_mfma_f32_16x16x32_bf16((a), (b), (c), 0, 0, 0)

__device__ __forceinline__ void async16(__bf16* lds_p, const __bf16* g) {
    __builtin_amdgcn_global_load_lds(
        (__attribute__((address_space(1))) void*)g,
        (__attribute__((address_space(3))) void*)lds_p, 16, 0, 0);
}

// ---------------------------------------------------------------------------
// prep: one grid-stride BW pass (unchanged from round 2).
// ---------------------------------------------------------------------------
__global__ __launch_bounds__(256) void prep(
    const float* __restrict__ q, const float* __restrict__ k, const float* __restrict__ v,
    const float* __restrict__ wq, const float* __restrict__ wk,
    const float* __restrict__ wv, const float* __restrict__ wo,
    const float* __restrict__ ck, const float* __restrict__ cv,
    float* __restrict__ nk, float* __restrict__ nv,
    __bf16* __restrict__ dq, __bf16* __restrict__ dk, __bf16* __restrict__ dv,
    __bf16* __restrict__ dwq, __bf16* __restrict__ dwk,
    __bf16* __restrict__ dwv, __bf16* __restrict__ dwo,
    __bf16* __restrict__ ckb, __bf16* __restrict__ cvb) {
    const int nthreads = gridDim.x * blockDim.x;
    for (int i = blockIdx.x * blockDim.x + threadIdx.x; i < 9437184; i += nthreads) {
        if (i < 4194304) {
            const int sel = i >> 21;
            const int j = i & 2097151;
            const int dh4 = j & 31;
            const int t = (j >> 5) & 1023;
            const int h = (j >> 15) & 15;
            const int b = j >> 19;
            const float* src = sel ? cv : ck;
            float* dst = sel ? nv : nk;
            __bf16* dstb = sel ? cvb : ckb;
            const size_t si = ((size_t)(b << 10) + t) * 2048 + (h << 7) + (dh4 << 2);
            const size_t di = ((size_t)b << 22) + ((size_t)h << 18) + (t << 7) + (dh4 << 2);
            const size_t bi = (((size_t)(b * 16 + h) * 1024 + t) << 7) + (dh4 << 2);
            const f32x4 x = *(const f32x4*)&src[si];
            *(f32x4*)&dst[di] = x;
            bf16x4 bx;
#pragma unroll
            for (int e = 0; e < 4; e++) bx[e] = (__bf16)x[e];
            *(bf16x4*)&dstb[bi] = bx;
        } else {
            const float* s;
            __bf16* d;
            int off;
            if (i < 7340032) {
                const int ii = i - 4194304;
                const int r = ii >> 20;
                off = ii & 1048575;
                s = (r == 0) ? q : (r == 1) ? k : v;
                d = (r == 0) ? dq : (r == 1) ? dk : dv;
            } else {
                const int ii = i - 7340032;
                const int r = ii >> 19;
                off = ii & 524287;
                s = (r == 0) ? wq : (r == 1) ? wk : (r == 2) ? wv : wo;
                d = (r == 0) ? dwq : (r == 1) ? dwk : (r == 2) ? dwv : dwo;
            }
            const f32x4 x0 = *(const f32x4*)(s + (size_t)off * 8);
            const f32x4 x1 = *(const f32x4*)(s + (size_t)off * 8 + 4);
            bf16x8 o;
#pragma unroll
            for (int j2 = 0; j2 < 4; j2++) {
                o[j2]     = (__bf16)x0[j2];
                o[j2 + 4] = (__bf16)x1[j2];
            }
            *(bf16x8*)(d + (size_t)off * 8) = o;
        }
    }
}

// ---------------------------------------------------------------------------
// 256x256 8-phase GEMM, K=2048 (32 K-tiles of 64). 8 waves (2M x 4N), each
// owns a 128x64 output tile (acc[8][4] f32x4). LDS 128KB = 2 buffers x
// {A kk0, A kk1, B kk0, B kk1} halves of 16KB, each = 16 subtiles of
// 16rows x 32cols bf16 (1KB). Subtile inner swizzle: rows 8-15 swap their
// two 32B chunks (pre-swizzled global source, linear gload_lds dest) ->
// ds_read_b128 column reads are 4-way instead of 16-way.
// Per phase: {ds_read frags | stage 1 half | barrier | lgkmcnt(0) |
// setprio(1) 16 MFMA setprio(0) | barrier}; vmcnt(4) once per K-tile
// (phase p3), vmcnt(0) only for the last 2 tiles. Stage slots per tile T:
// p0:(T+1).A_kk1  p1:(T+1).B_kk1  p2:(T+2).A_kk0  p3:(T+2).B_kk0 — each
// half is published by a vmcnt+barrier >=1 phase before its first read.
// MODE 0: C0 = fp32 out[4096][2048] (+bias b0). MODE 1: fused QKV, seg by
// m-block: 0->ws_q bf16 scatter, 1/2 -> new_k/new_v fp32 (+1024 t offset).
// ---------------------------------------------------------------------------
template <int MODE>
__global__ __launch_bounds__(512, 2) void gemm8(
    const __bf16* __restrict__ A,
    const __bf16* __restrict__ W0, const __bf16* __restrict__ W1,
    const __bf16* __restrict__ W2,
    const float* __restrict__ bz0, const float* __restrict__ bz1,
    const float* __restrict__ bz2,
    void* __restrict__ C0, float* __restrict__ C1, float* __restrict__ C2) {
    extern __shared__ __bf16 lds[];
    constexpr int K = 2048;
    const int tid = threadIdx.x;
    const int w = tid >> 6, lane = tid & 63;
    const int wm = w >> 2, wn = w & 3;
    const int g = lane >> 4, c = lane & 15;

    const int lin = blockIdx.x;
    const int nb = lin & 7, mb = lin >> 3;   // nb==XCD id: W n-panel pinned per XCD
    const int m0 = mb << 8, n0 = nb << 8;
    const int seg = (MODE == 1) ? (mb >> 4) : 0;
    const __bf16* W = (MODE == 0 || seg == 0) ? W0 : (seg == 1) ? W1 : W2;
    const float* bias = (MODE == 0) ? bz0 : (seg == 0) ? bz0 : (seg == 1) ? bz1 : bz2;

    const __bf16* Ab = A + (size_t)m0 * K;
    const __bf16* Wb = W + (size_t)n0 * K;

    // staging: lane l covers subtile row l>>2, 16B chunk (l&3)^swz (swz=2 for
    // rows 8-15) -> LDS linear dest holds the swizzled layout.
    const int sch = (lane & 3) ^ (((lane >> 5) & 1) << 1);
    const int srow = lane >> 2;
    // frag read offset within a 16KB half (bf16 units): row c, chunk g^swz(c)
    const int foff = c * 32 + ((g ^ ((c >> 3) << 1)) << 3);
    const int arow0 = wm * 8;   // A subtile base (wave's 128 rows)
    const int brow0 = wn * 4;   // B subtile base (wave's 64 rows)

    f32x4 acc[8][4] = {};

    auto stg = [&](const __bf16* src, int T, int kk, int region, int bf) {
#pragma unroll
        for (int cc = 0; cc < 2; cc++) {
            const __bf16* gs = src + (size_t)((cc * 8 + w) * 16 + srow) * K
                             + T * 64 + kk * 32 + sch * 8;
            async16(&lds[bf * 32768 + region * 16384 + kk * 8192 + (cc * 8 + w) * 512], gs);
        }
    };

    // prologue: tiles 0 (buf0) and 1 (buf1), full drain
    stg(Ab, 0, 0, 0, 0); stg(Wb, 0, 0, 1, 0);
    stg(Ab, 0, 1, 0, 0); stg(Wb, 0, 1, 1, 0);
    stg(Ab, 1, 0, 0, 1); stg(Wb, 1, 0, 1, 1);
    stg(Ab, 1, 1, 0, 1); stg(Wb, 1, 1, 1, 1);
    asm volatile("s_waitcnt vmcnt(0)" ::: "memory");
    asm volatile("s_barrier" ::: "memory");

#pragma unroll 2
    for (int T = 0; T < 32; T++) {
        const int bf = T & 1;
        const int ab = bf * 32768;
        const int bb = bf * 32768 + 16384;
        bf16x8 fa[4], fb[4], fb2[4];

        // ---- p0: A(mh0,kk0) + B(kk0); stage (T+1).A_kk1 -> other buf
#pragma unroll
        for (int i = 0; i < 4; i++)
            fa[i] = *(const bf16x8*)&lds[ab + (arow0 + i) * 512 + foff];
#pragma unroll
        for (int j = 0; j < 4; j++)
            fb[j] = *(const bf16x8*)&lds[bb + (brow0 + j) * 512 + foff];
        if (T >= 1 && T <= 30) stg(Ab, T + 1, 1, 0, bf ^ 1);
        asm volatile("s_barrier" ::: "memory");
        asm volatile("s_waitcnt lgkmcnt(0)" ::: "memory");
        __builtin_amdgcn_sched_barrier(0);
        __builtin_amdgcn_s_setprio(1);
#pragma unroll
        for (int i = 0; i < 4; i++)
#pragma unroll
            for (int j = 0; j < 4; j++)
                acc[i][j] = MFMA16(fa[i], fb[j], acc[i][j]);
        __builtin_amdgcn_s_setprio(0);
        asm volatile("s_barrier" ::: "memory");

        // ---- p1: A(mh1,kk0); stage (T+1).B_kk1 -> other buf
#pragma unroll
        for (int i = 0; i < 4; i++)
            fa[i] = *(const bf16x8*)&lds[ab + (arow0 + 4 + i) * 512 + foff];
        if (T >= 1 && T <= 30) stg(Wb, T + 1, 1, 1, bf ^ 1);
        asm volatile("s_barrier" ::: "memory");
        asm volatile("s_waitcnt lgkmcnt(0)" ::: "memory");
        __builtin_amdgcn_sched_barrier(0);
        __builtin_amdgcn_s_setprio(1);
#pragma unroll
        for (int i = 0; i < 4; i++)
#pragma unroll
            for (int j = 0; j < 4; j++)
                acc[4 + i][j] = MFMA16(fa[i], fb[j], acc[4 + i][j]);
        __builtin_amdgcn_s_setprio(0);
        asm volatile("s_barrier" ::: "memory");

        // ---- p2: A(mh0,kk1) + B(kk1); stage (T+2).A_kk0 -> this buf
#pragma unroll
        for (int i = 0; i < 4; i++)
            fa[i] = *(const bf16x8*)&lds[ab + 8192 + (arow0 + i) * 512 + foff];
#pragma unroll
        for (int j = 0; j < 4; j++)
            fb2[j] = *(const bf16x8*)&lds[bb + 8192 + (brow0 + j) * 512 + foff];
        if (T <= 29) stg(Ab, T + 2, 0, 0, bf);
        asm volatile("s_barrier" ::: "memory");
        asm volatile("s_waitcnt lgkmcnt(0)" ::: "memory");
        __builtin_amdgcn_sched_barrier(0);
        __builtin_amdgcn_s_setprio(1);
#pragma unroll
        for (int i = 0; i < 4; i++)
#pragma unroll
            for (int j = 0; j < 4; j++)
                acc[i][j] = MFMA16(fa[i], fb2[j], acc[i][j]);
        __builtin_amdgcn_s_setprio(0);
        asm volatile("s_barrier" ::: "memory");

        // ---- p3: A(mh1,kk1); stage (T+2).B_kk0 -> this buf; counted vmcnt
#pragma unroll
        for (int i = 0; i < 4; i++)
            fa[i] = *(const bf16x8*)&lds[ab + 8192 + (arow0 + 4 + i) * 512 + foff];
        if (T <= 29) stg(Wb, T + 2, 0, 1, bf);
        if (T >= 30) asm volatile("s_waitcnt vmcnt(0)" ::: "memory");
        else         asm volatile("s_waitcnt vmcnt(4)" ::: "memory");
        asm volatile("s_barrier" ::: "memory");
        asm volatile("s_waitcnt lgkmcnt(0)" ::: "memory");
        __builtin_amdgcn_sched_barrier(0);
        __builtin_amdgcn_s_setprio(1);
#pragma unroll
        for (int i = 0; i < 4; i++)
#pragma unroll
            for (int j = 0; j < 4; j++)
                acc[4 + i][j] = MFMA16(fa[i], fb2[j], acc[4 + i][j]);
        __builtin_amdgcn_s_setprio(0);
        asm volatile("s_barrier" ::: "memory");
    }

    // epilogue
#pragma unroll
    for (int mi = 0; mi < 8; mi++) {
#pragma unroll
        for (int ni = 0; ni < 4; ni++) {
            const int col = n0 + wn * 64 + ni * 16 + c;
            const float bv = bias[col];
            const int rowb = m0 + wm * 128 + mi * 16 + g * 4;
            if (MODE == 0) {
                float* Cf = (float*)C0;
#pragma unroll
                for (int r = 0; r < 4; r++)
                    Cf[(size_t)(rowb + r) * 2048 + col] = acc[mi][ni][r] + bv;
            } else {
                const int h = col >> 7, dh = col & 127;
#pragma unroll
                for (int r = 0; r < 4; r++) {
                    const float v = acc[mi][ni][r] + bv;
                    const int lrow = (rowb + r) & 4095;
                    const int b = lrow >> 10, t = lrow & 1023;
                    if (seg == 0)
                        ((__bf16*)C0)[(((size_t)(b * 16 + h) * 1024) + t) * 128 + dh] = (__bf16)v;
                    else if (seg == 1)
                        C1[(((size_t)(b * 16 + h) * 2048) + 1024 + t) * 128 + dh] = v;
                    else
                        C2[(((size_t)(b * 16 + h) * 2048) + 1024 + t) * 128 + dh] = v;
                }
            }
        }
    }
}

// ---------------------------------------------------------------------------
// Flash attention (round-1 structure, measured 112us), staged from bf16
// HEAD-MAJOR cache mirrors [b][h][1024][128] -> contiguous 2KB/wave reads.
// KVBLK=32, 4 waves x 16 q-rows, balanced chunk-reflected dispatch map.
// ---------------------------------------------------------------------------
__global__ __launch_bounds__(256) void attn_k(const __bf16* __restrict__ Qw,
                                              const __bf16* __restrict__ cK,
                                              const __bf16* __restrict__ cV,
                                              __bf16* __restrict__ O) {
    __shared__ __bf16 Kt[32 * 128];
    __shared__ u32 Vt32[128 * 16];
    __shared__ __bf16 Pw[4][16 * 32];

    const int tid = threadIdx.x;
    const int w = tid >> 6;
    const int lane = tid & 63;
    const int g = lane >> 4, c = lane & 15;

    const int lin = blockIdx.x + (blockIdx.y << 4) + (blockIdx.z << 8);
    const int chunk = lin >> 8, idx = lin & 255;
    int qb = idx & 15;
    if (chunk & 1) qb = 15 - qb;
    const int bh = (idx >> 4) + (chunk << 4);
    const int b = bh >> 4, h = bh & 15;
    const int q0 = qb << 6;
    const float inv_scale = 0.08838834764831845f; // 1/sqrt(128)

    const __bf16* qbase = Qw + (((size_t)(b * 16 + h) * 1024) + q0 + w * 16) * 128;
    bf16x8 qf[4];
#pragma unroll
    for (int dc = 0; dc < 4; dc++)
        qf[dc] = *(const bf16x8*)&qbase[c * 128 + dc * 32 + g * 8];

    f32x4 accO[8] = {};
    float m_run[4], l_run[4];
#pragma unroll
    for (int r = 0; r < 4; r++) { m_run[r] = -1e30f; l_run[r] = 0.0f; }

    const int trips = (q0 >> 5) + 2;
    const __bf16* kb = cK + (size_t)(b * 16 + h) * 1024 * 128;
    const __bf16* vb = cV + (size_t)(b * 16 + h) * 1024 * 128;

    const int skey = tid >> 3, sdh = (tid & 7) * 16;
    const int kp = tid >> 4, db = tid & 15;
    const int vcol = (((kp >> 2) ^ (db & 3)) << 2) | (kp & 3);

    for (int kt = 0; kt < trips; kt++) {
        const int k0 = kt * 32;
        const bf16x8 k_lo = *(const bf16x8*)&kb[(size_t)(k0 + skey) * 128 + sdh];
        const bf16x8 k_hi = *(const bf16x8*)&kb[(size_t)(k0 + skey) * 128 + sdh + 8];
        const bf16x8 v0 = *(const bf16x8*)&vb[(size_t)(k0 + 2 * kp) * 128 + db * 8];
        const bf16x8 v1 = *(const bf16x8*)&vb[(size_t)(k0 + 2 * kp + 1) * 128 + db * 8];
        __syncthreads();   // prior iteration's Kt/Vt reads complete
        {
            const int ss = skey & 7, ch0 = (tid & 7) * 2;
            *(bf16x8*)&Kt[skey * 128 + ((ch0 ^ ss) << 3)]       = k_lo;
            *(bf16x8*)&Kt[skey * 128 + (((ch0 + 1) ^ ss) << 3)] = k_hi;
        }
        {
            const u16x8 pa = __builtin_bit_cast(u16x8, v0);
            const u16x8 pb = __builtin_bit_cast(u16x8, v1);
#pragma unroll
            for (int j = 0; j < 8; j++)
                Vt32[(db * 8 + j) * 16 + vcol] = (u32)pa[j] | ((u32)pb[j] << 16);
        }
        __syncthreads();   // staging visible

        f32x4 s_acc[2] = {};
#pragma unroll
        for (int nt = 0; nt < 2; nt++) {
            const int krow = nt * 16 + c;
            const int ks = krow & 7;
#pragma unroll
            for (int dc = 0; dc < 4; dc++) {
                const bf16x8 kf =
                    *(const bf16x8*)&Kt[krow * 128 + (((dc * 4 + g) ^ ks) << 3)];
                s_acc[nt] = MFMA16(qf[dc], kf, s_acc[nt]);
            }
        }

        float p[2][4], alpha[4];
#pragma unroll
        for (int r = 0; r < 4; r++) {
            const int qrow = q0 + w * 16 + g * 4 + r;
            float s0 = (k0 + c      <= qrow) ? s_acc[0][r] * inv_scale : -1e30f;
            float s1 = (k0 + 16 + c <= qrow) ? s_acc[1][r] * inv_scale : -1e30f;
            float rm = fmaxf(s0, s1);
            rm = fmaxf(rm, __shfl_xor(rm, 1));
            rm = fmaxf(rm, __shfl_xor(rm, 2));
            rm = fmaxf(rm, __shfl_xor(rm, 4));
            rm = fmaxf(rm, __shfl_xor(rm, 8));
            const float mnew = fmaxf(m_run[r], rm);
            alpha[r] = __expf(m_run[r] - mnew);
            const float p0 = __expf(s0 - mnew);
            const float p1 = __expf(s1 - mnew);
            p[0][r] = p0; p[1][r] = p1;
            float ps = p0 + p1;
            ps += __shfl_xor(ps, 1);
            ps += __shfl_xor(ps, 2);
            ps += __shfl_xor(ps, 4);
            ps += __shfl_xor(ps, 8);
            l_run[r] = alpha[r] * l_run[r] + ps;
            m_run[r] = mnew;
        }
#pragma unroll
        for (int nt2 = 0; nt2 < 8; nt2++)
#pragma unroll
            for (int r = 0; r < 4; r++)
                accO[nt2][r] *= alpha[r];

#pragma unroll
        for (int nt = 0; nt < 2; nt++)
#pragma unroll
            for (int r = 0; r < 4; r++)
                Pw[w][(g * 4 + r) * 32 + ((((nt << 1) | (c >> 3)) ^ g) << 3) + (c & 7)] =
                    (__bf16)p[nt][r];
        asm volatile("s_waitcnt lgkmcnt(0)" ::: "memory");
        __builtin_amdgcn_sched_barrier(0);

        const bf16x8 pf = *(const bf16x8*)&Pw[w][c * 32 + ((g ^ ((c >> 2) & 3)) << 3)];
#pragma unroll
        for (int nt2 = 0; nt2 < 8; nt2++) {
            const int vrow = nt2 * 16 + c;
            const bf16x8 vf = *(const bf16x8*)&(
                (const __bf16*)Vt32)[vrow * 32 + ((g ^ ((vrow >> 3) & 3)) << 3)];
            accO[nt2] = MFMA16(pf, vf, accO[nt2]);
        }
    }

#pragma unroll
    for (int nt2 = 0; nt2 < 8; nt2++)
#pragma unroll
        for (int r = 0; r < 4; r++) {
            const float v = accO[nt2][r] / l_run[r];
            const int row = b * 1024 + q0 + w * 16 + g * 4 + r;
            const int col = h * 128 + nt2 * 16 + c;
            O[(size_t)row * 2048 + col] = (__bf16)v;
        }
}

// ---------------------------------------------------------------------------
extern "C" void kernel_launch(void* const* d_in, const int* in_sizes, int n_in,
                              void* d_out, int out_size, void* d_ws, size_t ws_size,
                              hipStream_t stream) {
    const float* query       = (const float*)d_in[0];
    const float* key         = (const float*)d_in[1];
    const float* value       = (const float*)d_in[2];
    const float* cache_key   = (const float*)d_in[3];
    const float* cache_value = (const float*)d_in[4];
    const float* Wq = (const float*)d_in[5];
    const float* bq = (const float*)d_in[6];
    const float* Wk = (const float*)d_in[7];
    const float* bk = (const float*)d_in[8];
    const float* Wv = (const float*)d_in[9];
    const float* bv = (const float*)d_in[10];
    const float* Wo = (const float*)d_in[11];
    const float* bo = (const float*)d_in[12];

    float* out   = (float*)d_out;              // [4096][2048] fp32
    float* new_k = out + 8388608;              // [B][H][2048][128] fp32
    float* new_v = out + 25165824;

    // workspace (bf16 elems): q_bf/k_bf/v_bf MUST be contiguous (A-concat)
    __bf16* p = (__bf16*)d_ws;
    __bf16* ws_q    = p; p += 8388608;         // [b][h][1024][128]
    __bf16* ws_attn = p; p += 8388608;         // [4096][2048]
    __bf16* q_bf    = p; p += 8388608;         // A-concat rows 0..4095
    __bf16* k_bf    = p; p += 8388608;         //               4096..8191
    __bf16* v_bf    = p; p += 8388608;         //               8192..12287
    __bf16* wq_bf   = p; p += 4194304;
    __bf16* wk_bf   = p; p += 4194304;
    __bf16* wv_bf   = p; p += 4194304;
    __bf16* wo_bf   = p; p += 4194304;
    __bf16* ck_bf   = p; p += 8388608;         // [b][h][1024][128] head-major
    __bf16* cv_bf   = p;

    static bool s_attr = false;
    if (!s_attr) {
        hipFuncSetAttribute(reinterpret_cast<const void*>(&gemm8<1>),
                            hipFuncAttributeMaxDynamicSharedMemorySize, 131072);
        hipFuncSetAttribute(reinterpret_cast<const void*>(&gemm8<0>),
                            hipFuncAttributeMaxDynamicSharedMemorySize, 131072);
        s_attr = true;
    }

    prep<<<4096, 256, 0, stream>>>(query, key, value, Wq, Wk, Wv, Wo,
                                   cache_key, cache_value, new_k, new_v,
                                   q_bf, k_bf, v_bf, wq_bf, wk_bf, wv_bf, wo_bf,
                                   ck_bf, cv_bf);
    gemm8<1><<<384, 512, 131072, stream>>>(q_bf, wq_bf, wk_bf, wv_bf,
                                           bq, bk, bv, ws_q, new_k, new_v);
    attn_k<<<dim3(16, 16, 4), 256, 0, stream>>>(ws_q, ck_bf, cv_bf, ws_attn);
    gemm8<0><<<128, 512, 131072, stream>>>(ws_attn, wo_bf, nullptr, nullptr,
                                           bo, nullptr, nullptr, out, nullptr, nullptr);
}

// Round 4
// 618.413 us; speedup vs baseline: 1.0861x; 1.0356x over previous
//
#include <hip/hip_runtime.h>
#include <hip/hip_bf16.h>

// ---------------------------------------------------------------------------
// KV-cached MHA, MI355X. Round 4:
//  * gemm8 re-tiled BM=128 x BN=256 x BK=64, 8 waves (2Mx4N, wave 64x64),
//    LDS ring-of-3 regions (3 x {A 16KB + B 32KB} = 144 KB): tile T read,
//    T+1 landed, T+2 streaming -> stage issued 4 phases ahead of its
//    vmcnt(6) wait, no region conflicts (distinct mod 3).
//    qkv: 768 blocks = exactly 3 block-waves (was 384 = 1.5 -> 25% idle).
//    out-proj: 256 blocks = exactly 1 block-wave (was 128 = 50% idle).
//  * prep: 32B/thread units in the cache segment (full-width stores).
//  * attn unchanged from round 3.
// ---------------------------------------------------------------------------

typedef __bf16 bf16x8 __attribute__((ext_vector_type(8)));
typedef unsigned short u16x8 __attribute__((ext_vector_type(8)));
typedef float  f32x4  __attribute__((ext_vector_type(4)));
typedef unsigned int u32;

#define MFMA16(a, b, c) __builtin_amdgcn_mfma_f32_16x16x32_bf16((a), (b), (c), 0, 0, 0)

__device__ __forceinline__ void async16(__bf16* lds_p, const __bf16* g) {
    __builtin_amdgcn_global_load_lds(
        (__attribute__((address_space(1))) void*)g,
        (__attribute__((address_space(3))) void*)lds_p, 16, 0, 0);
}

// ---------------------------------------------------------------------------
// prep: one grid-stride BW pass.
//  seg A (2^21 units, 32B each): cache fp32 copy -> new_k/new_v + bf16
//                                head-major mirrors
//  seg B (3*2^20 units): q/k/v fp32 -> bf16 (8 elems/unit)
//  seg C (2^21 units): Wq/Wk/Wv/Wo fp32 -> bf16 (8 elems/unit)
// ---------------------------------------------------------------------------
__global__ __launch_bounds__(256) void prep(
    const float* __restrict__ q, const float* __restrict__ k, const float* __restrict__ v,
    const float* __restrict__ wq, const float* __restrict__ wk,
    const float* __restrict__ wv, const float* __restrict__ wo,
    const float* __restrict__ ck, const float* __restrict__ cv,
    float* __restrict__ nk, float* __restrict__ nv,
    __bf16* __restrict__ dq, __bf16* __restrict__ dk, __bf16* __restrict__ dv,
    __bf16* __restrict__ dwq, __bf16* __restrict__ dwk,
    __bf16* __restrict__ dwv, __bf16* __restrict__ dwo,
    __bf16* __restrict__ ckb, __bf16* __restrict__ cvb) {
    const int nthreads = gridDim.x * blockDim.x;
    for (int i = blockIdx.x * blockDim.x + threadIdx.x; i < 7340032; i += nthreads) {
        if (i < 2097152) {
            const int sel = i >> 20;
            const int j = i & 1048575;
            const int dh8 = j & 15;
            const int t = (j >> 4) & 1023;
            const int h = (j >> 14) & 15;
            const int b = j >> 18;
            const float* src = sel ? cv : ck;
            float* dst = sel ? nv : nk;
            __bf16* dstb = sel ? cvb : ckb;
            const size_t si = ((size_t)(b << 10) + t) * 2048 + (h << 7) + (dh8 << 3);
            const size_t di = ((size_t)b << 22) + ((size_t)h << 18) + (t << 7) + (dh8 << 3);
            const size_t bi = (((size_t)(b * 16 + h) * 1024 + t) << 7) + (dh8 << 3);
            const f32x4 x0 = *(const f32x4*)&src[si];
            const f32x4 x1 = *(const f32x4*)&src[si + 4];
            *(f32x4*)&dst[di] = x0;
            *(f32x4*)&dst[di + 4] = x1;
            bf16x8 bx;
#pragma unroll
            for (int e = 0; e < 4; e++) {
                bx[e]     = (__bf16)x0[e];
                bx[e + 4] = (__bf16)x1[e];
            }
            *(bf16x8*)&dstb[bi] = bx;
        } else {
            const float* s;
            __bf16* d;
            int off;
            if (i < 5242880) {
                const int ii = i - 2097152;
                const int r = ii >> 20;
                off = ii & 1048575;
                s = (r == 0) ? q : (r == 1) ? k : v;
                d = (r == 0) ? dq : (r == 1) ? dk : dv;
            } else {
                const int ii = i - 5242880;
                const int r = ii >> 19;
                off = ii & 524287;
                s = (r == 0) ? wq : (r == 1) ? wk : (r == 2) ? wv : wo;
                d = (r == 0) ? dwq : (r == 1) ? dwk : (r == 2) ? dwv : dwo;
            }
            const f32x4 x0 = *(const f32x4*)(s + (size_t)off * 8);
            const f32x4 x1 = *(const f32x4*)(s + (size_t)off * 8 + 4);
            bf16x8 o;
#pragma unroll
            for (int j2 = 0; j2 < 4; j2++) {
                o[j2]     = (__bf16)x0[j2];
                o[j2 + 4] = (__bf16)x1[j2];
            }
            *(bf16x8*)(d + (size_t)off * 8) = o;
        }
    }
}

// ---------------------------------------------------------------------------
// 128x256 8-phase GEMM, K=2048 (32 K-tiles of 64). 8 waves (2M x 4N), each
// owns a 64x64 output tile (acc[4][4]). LDS = ring of 3 regions x
// {A 16KB + B 32KB}; subtiles 16x32 bf16 (1KB) with the round-3 chunk
// swizzle (rows 8-15 swap 32B chunks; pre-swizzled global source, linear
// gload_lds dest) -> conflict-free ds_read_b128 (measured 0).
// Per tile: 2 phases (kk halves) x {8 ds_read | stage | (wait) | barrier |
// lgkmcnt(0) | setprio 16 MFMA | barrier}. Stage slots: tile T stages
// (T+2).A at p0, (T+2).B at p1; vmcnt(6) at p1 leaves exactly (T+2)'s 6
// loads -> (T+1) complete, issued 4 phases before the wait. Regions
// T, T+1, T+2 are distinct mod 3 -> streaming never hits a live buffer.
// MODE 0: C0 fp32 out[4096][2048]. MODE 1: fused QKV (seg = mb>>5):
// 0 -> ws_q bf16 scatter, 1/2 -> new_k/new_v fp32 (t offset +1024).
// ---------------------------------------------------------------------------
template <int MODE>
__global__ __launch_bounds__(512, 2) void gemm8(
    const __bf16* __restrict__ A,
    const __bf16* __restrict__ W0, const __bf16* __restrict__ W1,
    const __bf16* __restrict__ W2,
    const float* __restrict__ bz0, const float* __restrict__ bz1,
    const float* __restrict__ bz2,
    void* __restrict__ C0, float* __restrict__ C1, float* __restrict__ C2) {
    extern __shared__ __bf16 lds[];
    constexpr int K = 2048;
    const int tid = threadIdx.x;
    const int w = tid >> 6, lane = tid & 63;
    const int wm = w >> 2, wn = w & 3;
    const int g = lane >> 4, c = lane & 15;

    const int lin = blockIdx.x;
    const int nb = lin & 7, mb = lin >> 3;   // nb == XCD id: W panel per XCD
    const int m0 = mb << 7, n0 = nb << 8;
    const int seg = (MODE == 1) ? (mb >> 5) : 0;
    const __bf16* W = (MODE == 0 || seg == 0) ? W0 : (seg == 1) ? W1 : W2;
    const float* bias = (MODE == 0) ? bz0 : (seg == 0) ? bz0 : (seg == 1) ? bz1 : bz2;

    const __bf16* Ab = A + (size_t)m0 * K;
    const __bf16* Wb = W + (size_t)n0 * K;

    const int srow = lane >> 2;                               // staging row in subtile
    const int sch = (lane & 3) ^ (((lane >> 5) & 1) << 1);    // pre-swizzled chunk
    const int foff = c * 32 + ((g ^ ((c >> 3) << 1)) << 3);   // frag read offset

    f32x4 acc[4][4] = {};

    // A region: 8 row-subtiles x 2 kk, subtile s = rowblk*2+kk at s*512.
    // Wave w stages rowblk w (both kk) = 2 async16.
    auto stgA = [&](int T, int rg) {
#pragma unroll
        for (int u = 0; u < 2; u++) {
            const __bf16* gs = Ab + (size_t)(w * 16 + srow) * K + T * 64 + u * 32 + sch * 8;
            async16(&lds[rg * 24576 + (w * 2 + u) * 512], gs);
        }
    };
    // B region: 16 row-subtiles x 2 kk at 8192 + s*512. Wave w stages 4.
    auto stgB = [&](int T, int rg) {
#pragma unroll
        for (int u = 0; u < 4; u++) {
            const int rowblk = 2 * w + (u >> 1), kk = u & 1;
            const __bf16* gs = Wb + (size_t)(rowblk * 16 + srow) * K + T * 64 + kk * 32 + sch * 8;
            async16(&lds[rg * 24576 + 8192 + (w * 4 + u) * 512], gs);
        }
    };

    // prologue: tiles 0 -> region 0, 1 -> region 1; require tile 0 complete
    stgA(0, 0); stgB(0, 0);
    stgA(1, 1); stgB(1, 1);
    asm volatile("s_waitcnt vmcnt(6)" ::: "memory");
    asm volatile("s_barrier" ::: "memory");

    int rg = 0;
    for (int T = 0; T < 32; T++) {
        int rs = rg + 2; if (rs >= 3) rs -= 3;
        const int base = rg * 24576;
        bf16x8 fa[4], fb[4];

        // ---- p0 (kk=0): read frags, stage (T+2).A
#pragma unroll
        for (int mi = 0; mi < 4; mi++)
            fa[mi] = *(const bf16x8*)&lds[base + ((wm * 4 + mi) * 2 + 0) * 512 + foff];
#pragma unroll
        for (int ni = 0; ni < 4; ni++)
            fb[ni] = *(const bf16x8*)&lds[base + 8192 + ((wn * 4 + ni) * 2 + 0) * 512 + foff];
        if (T < 30) stgA(T + 2, rs);
        asm volatile("s_barrier" ::: "memory");
        asm volatile("s_waitcnt lgkmcnt(0)" ::: "memory");
        __builtin_amdgcn_sched_barrier(0);
        __builtin_amdgcn_s_setprio(1);
#pragma unroll
        for (int mi = 0; mi < 4; mi++)
#pragma unroll
            for (int ni = 0; ni < 4; ni++)
                acc[mi][ni] = MFMA16(fa[mi], fb[ni], acc[mi][ni]);
        __builtin_amdgcn_s_setprio(0);
        asm volatile("s_barrier" ::: "memory");

        // ---- p1 (kk=1): read frags, stage (T+2).B, counted wait
#pragma unroll
        for (int mi = 0; mi < 4; mi++)
            fa[mi] = *(const bf16x8*)&lds[base + ((wm * 4 + mi) * 2 + 1) * 512 + foff];
#pragma unroll
        for (int ni = 0; ni < 4; ni++)
            fb[ni] = *(const bf16x8*)&lds[base + 8192 + ((wn * 4 + ni) * 2 + 1) * 512 + foff];
        if (T < 30) {
            stgB(T + 2, rs);
            asm volatile("s_waitcnt vmcnt(6)" ::: "memory");
        } else {
            asm volatile("s_waitcnt vmcnt(0)" ::: "memory");
        }
        asm volatile("s_barrier" ::: "memory");
        asm volatile("s_waitcnt lgkmcnt(0)" ::: "memory");
        __builtin_amdgcn_sched_barrier(0);
        __builtin_amdgcn_s_setprio(1);
#pragma unroll
        for (int mi = 0; mi < 4; mi++)
#pragma unroll
            for (int ni = 0; ni < 4; ni++)
                acc[mi][ni] = MFMA16(fa[mi], fb[ni], acc[mi][ni]);
        __builtin_amdgcn_s_setprio(0);
        asm volatile("s_barrier" ::: "memory");

        rg = (rg + 1 == 3) ? 0 : rg + 1;
    }

    // epilogue: C/D layout col = lane&15 (n), row = (lane>>4)*4 + reg (m)
#pragma unroll
    for (int ni = 0; ni < 4; ni++) {
        const int col = n0 + wn * 64 + ni * 16 + c;
        const float bv = bias[col];
        const int h = col >> 7, dh = col & 127;
#pragma unroll
        for (int mi = 0; mi < 4; mi++) {
            const int rowb = m0 + wm * 64 + mi * 16 + g * 4;
#pragma unroll
            for (int r = 0; r < 4; r++) {
                const float v = acc[mi][ni][r] + bv;
                if (MODE == 0) {
                    ((float*)C0)[(size_t)(rowb + r) * 2048 + col] = v;
                } else {
                    const int lrow = (rowb + r) & 4095;
                    const int b = lrow >> 10, t = lrow & 1023;
                    if (seg == 0)
                        ((__bf16*)C0)[(((size_t)(b * 16 + h) * 1024) + t) * 128 + dh] = (__bf16)v;
                    else if (seg == 1)
                        C1[(((size_t)(b * 16 + h) * 2048) + 1024 + t) * 128 + dh] = v;
                    else
                        C2[(((size_t)(b * 16 + h) * 2048) + 1024 + t) * 128 + dh] = v;
                }
            }
        }
    }
}

// ---------------------------------------------------------------------------
// Flash attention (round-3 version, unchanged): KVBLK=32, 4 waves x 16
// q-rows, bf16 head-major cache mirrors, swizzled Kt/Vt/Pw (conflict-light),
// balanced chunk-reflected dispatch map.
// ---------------------------------------------------------------------------
__global__ __launch_bounds__(256) void attn_k(const __bf16* __restrict__ Qw,
                                              const __bf16* __restrict__ cK,
                                              const __bf16* __restrict__ cV,
                                              __bf16* __restrict__ O) {
    __shared__ __bf16 Kt[32 * 128];
    __shared__ u32 Vt32[128 * 16];
    __shared__ __bf16 Pw[4][16 * 32];

    const int tid = threadIdx.x;
    const int w = tid >> 6;
    const int lane = tid & 63;
    const int g = lane >> 4, c = lane & 15;

    const int lin = blockIdx.x + (blockIdx.y << 4) + (blockIdx.z << 8);
    const int chunk = lin >> 8, idx = lin & 255;
    int qb = idx & 15;
    if (chunk & 1) qb = 15 - qb;
    const int bh = (idx >> 4) + (chunk << 4);
    const int b = bh >> 4, h = bh & 15;
    const int q0 = qb << 6;
    const float inv_scale = 0.08838834764831845f; // 1/sqrt(128)

    const __bf16* qbase = Qw + (((size_t)(b * 16 + h) * 1024) + q0 + w * 16) * 128;
    bf16x8 qf[4];
#pragma unroll
    for (int dc = 0; dc < 4; dc++)
        qf[dc] = *(const bf16x8*)&qbase[c * 128 + dc * 32 + g * 8];

    f32x4 accO[8] = {};
    float m_run[4], l_run[4];
#pragma unroll
    for (int r = 0; r < 4; r++) { m_run[r] = -1e30f; l_run[r] = 0.0f; }

    const int trips = (q0 >> 5) + 2;
    const __bf16* kb = cK + (size_t)(b * 16 + h) * 1024 * 128;
    const __bf16* vb = cV + (size_t)(b * 16 + h) * 1024 * 128;

    const int skey = tid >> 3, sdh = (tid & 7) * 16;
    const int kp = tid >> 4, db = tid & 15;
    const int vcol = (((kp >> 2) ^ (db & 3)) << 2) | (kp & 3);

    for (int kt = 0; kt < trips; kt++) {
        const int k0 = kt * 32;
        const bf16x8 k_lo = *(const bf16x8*)&kb[(size_t)(k0 + skey) * 128 + sdh];
        const bf16x8 k_hi = *(const bf16x8*)&kb[(size_t)(k0 + skey) * 128 + sdh + 8];
        const bf16x8 v0 = *(const bf16x8*)&vb[(size_t)(k0 + 2 * kp) * 128 + db * 8];
        const bf16x8 v1 = *(const bf16x8*)&vb[(size_t)(k0 + 2 * kp + 1) * 128 + db * 8];
        __syncthreads();   // prior iteration's Kt/Vt reads complete
        {
            const int ss = skey & 7, ch0 = (tid & 7) * 2;
            *(bf16x8*)&Kt[skey * 128 + ((ch0 ^ ss) << 3)]       = k_lo;
            *(bf16x8*)&Kt[skey * 128 + (((ch0 + 1) ^ ss) << 3)] = k_hi;
        }
        {
            const u16x8 pa = __builtin_bit_cast(u16x8, v0);
            const u16x8 pb = __builtin_bit_cast(u16x8, v1);
#pragma unroll
            for (int j = 0; j < 8; j++)
                Vt32[(db * 8 + j) * 16 + vcol] = (u32)pa[j] | ((u32)pb[j] << 16);
        }
        __syncthreads();   // staging visible

        f32x4 s_acc[2] = {};
#pragma unroll
        for (int nt = 0; nt < 2; nt++) {
            const int krow = nt * 16 + c;
            const int ks = krow & 7;
#pragma unroll
            for (int dc = 0; dc < 4; dc++) {
                const bf16x8 kf =
                    *(const bf16x8*)&Kt[krow * 128 + (((dc * 4 + g) ^ ks) << 3)];
                s_acc[nt] = MFMA16(qf[dc], kf, s_acc[nt]);
            }
        }

        float p[2][4], alpha[4];
#pragma unroll
        for (int r = 0; r < 4; r++) {
            const int qrow = q0 + w * 16 + g * 4 + r;
            float s0 = (k0 + c      <= qrow) ? s_acc[0][r] * inv_scale : -1e30f;
            float s1 = (k0 + 16 + c <= qrow) ? s_acc[1][r] * inv_scale : -1e30f;
            float rm = fmaxf(s0, s1);
            rm = fmaxf(rm, __shfl_xor(rm, 1));
            rm = fmaxf(rm, __shfl_xor(rm, 2));
            rm = fmaxf(rm, __shfl_xor(rm, 4));
            rm = fmaxf(rm, __shfl_xor(rm, 8));
            const float mnew = fmaxf(m_run[r], rm);
            alpha[r] = __expf(m_run[r] - mnew);
            const float p0 = __expf(s0 - mnew);
            const float p1 = __expf(s1 - mnew);
            p[0][r] = p0; p[1][r] = p1;
            float ps = p0 + p1;
            ps += __shfl_xor(ps, 1);
            ps += __shfl_xor(ps, 2);
            ps += __shfl_xor(ps, 4);
            ps += __shfl_xor(ps, 8);
            l_run[r] = alpha[r] * l_run[r] + ps;
            m_run[r] = mnew;
        }
#pragma unroll
        for (int nt2 = 0; nt2 < 8; nt2++)
#pragma unroll
            for (int r = 0; r < 4; r++)
                accO[nt2][r] *= alpha[r];

#pragma unroll
        for (int nt = 0; nt < 2; nt++)
#pragma unroll
            for (int r = 0; r < 4; r++)
                Pw[w][(g * 4 + r) * 32 + ((((nt << 1) | (c >> 3)) ^ g) << 3) + (c & 7)] =
                    (__bf16)p[nt][r];
        asm volatile("s_waitcnt lgkmcnt(0)" ::: "memory");
        __builtin_amdgcn_sched_barrier(0);

        const bf16x8 pf = *(const bf16x8*)&Pw[w][c * 32 + ((g ^ ((c >> 2) & 3)) << 3)];
#pragma unroll
        for (int nt2 = 0; nt2 < 8; nt2++) {
            const int vrow = nt2 * 16 + c;
            const bf16x8 vf = *(const bf16x8*)&(
                (const __bf16*)Vt32)[vrow * 32 + ((g ^ ((vrow >> 3) & 3)) << 3)];
            accO[nt2] = MFMA16(pf, vf, accO[nt2]);
        }
    }

#pragma unroll
    for (int nt2 = 0; nt2 < 8; nt2++)
#pragma unroll
        for (int r = 0; r < 4; r++) {
            const float v = accO[nt2][r] / l_run[r];
            const int row = b * 1024 + q0 + w * 16 + g * 4 + r;
            const int col = h * 128 + nt2 * 16 + c;
            O[(size_t)row * 2048 + col] = (__bf16)v;
        }
}

// ---------------------------------------------------------------------------
extern "C" void kernel_launch(void* const* d_in, const int* in_sizes, int n_in,
                              void* d_out, int out_size, void* d_ws, size_t ws_size,
                              hipStream_t stream) {
    const float* query       = (const float*)d_in[0];
    const float* key         = (const float*)d_in[1];
    const float* value       = (const float*)d_in[2];
    const float* cache_key   = (const float*)d_in[3];
    const float* cache_value = (const float*)d_in[4];
    const float* Wq = (const float*)d_in[5];
    const float* bq = (const float*)d_in[6];
    const float* Wk = (const float*)d_in[7];
    const float* bk = (const float*)d_in[8];
    const float* Wv = (const float*)d_in[9];
    const float* bv = (const float*)d_in[10];
    const float* Wo = (const float*)d_in[11];
    const float* bo = (const float*)d_in[12];

    float* out   = (float*)d_out;              // [4096][2048] fp32
    float* new_k = out + 8388608;              // [B][H][2048][128] fp32
    float* new_v = out + 25165824;

    // workspace (bf16 elems): q_bf/k_bf/v_bf MUST be contiguous (A-concat)
    __bf16* p = (__bf16*)d_ws;
    __bf16* ws_q    = p; p += 8388608;         // [b][h][1024][128]
    __bf16* ws_attn = p; p += 8388608;         // [4096][2048]
    __bf16* q_bf    = p; p += 8388608;         // A-concat rows 0..4095
    __bf16* k_bf    = p; p += 8388608;         //               4096..8191
    __bf16* v_bf    = p; p += 8388608;         //               8192..12287
    __bf16* wq_bf   = p; p += 4194304;
    __bf16* wk_bf   = p; p += 4194304;
    __bf16* wv_bf   = p; p += 4194304;
    __bf16* wo_bf   = p; p += 4194304;
    __bf16* ck_bf   = p; p += 8388608;         // [b][h][1024][128] head-major
    __bf16* cv_bf   = p;

    static bool s_attr = false;
    if (!s_attr) {
        hipFuncSetAttribute(reinterpret_cast<const void*>(&gemm8<1>),
                            hipFuncAttributeMaxDynamicSharedMemorySize, 147456);
        hipFuncSetAttribute(reinterpret_cast<const void*>(&gemm8<0>),
                            hipFuncAttributeMaxDynamicSharedMemorySize, 147456);
        s_attr = true;
    }

    prep<<<4096, 256, 0, stream>>>(query, key, value, Wq, Wk, Wv, Wo,
                                   cache_key, cache_value, new_k, new_v,
                                   q_bf, k_bf, v_bf, wq_bf, wk_bf, wv_bf, wo_bf,
                                   ck_bf, cv_bf);
    gemm8<1><<<768, 512, 147456, stream>>>(q_bf, wq_bf, wk_bf, wv_bf,
                                           bq, bk, bv, ws_q, new_k, new_v);
    attn_k<<<dim3(16, 16, 4), 256, 0, stream>>>(ws_q, ck_bf, cv_bf, ws_attn);
    gemm8<0><<<256, 512, 147456, stream>>>(ws_attn, wo_bf, nullptr, nullptr,
                                           bo, nullptr, nullptr, out, nullptr, nullptr);
}